// Round 1
// baseline (474.948 us; speedup 1.0000x reference)
//
#include <hip/hip_runtime.h>

typedef unsigned short u16;
typedef __attribute__((ext_vector_type(8))) short s16x8;
typedef __attribute__((ext_vector_type(4))) short s16x4;
typedef __attribute__((ext_vector_type(4))) float f32x4;

__device__ __forceinline__ u16 f2bf(float f) {
    unsigned int u;
    __builtin_memcpy(&u, &f, 4);
    unsigned int r = u + 0x7FFFu + ((u >> 16) & 1u);   // RNE
    return (u16)(r >> 16);
}

// packed f32 pair -> bf16 pair (RNE), lo = cvt(a), hi = cvt(b)
__device__ __forceinline__ unsigned int cvt_pk_bf16(float a, float b) {
    unsigned int r;
    asm("v_cvt_pk_bf16_f32 %0, %1, %2" : "=v"(r) : "v"(a), "v"(b));
    return r;
}

__device__ __forceinline__ void gl_lds16(const u16* g, u16* l) {
    __builtin_amdgcn_global_load_lds(
        (const __attribute__((address_space(1))) unsigned int*)g,
        (__attribute__((address_space(3))) unsigned int*)l,
        16, 0, 0);
}

// ---------------------------------------------------------------------------
// Transpose f32 -> bf16: out[c][r] = bf16(in[r][c]). grid = (cols/64, rows/64)
// ---------------------------------------------------------------------------
__global__ __launch_bounds__(256) void k_transpose(const float* __restrict__ in,
                                                   u16* __restrict__ out,
                                                   int rows, int cols) {
    __shared__ float tile[64][65];
    int bx = blockIdx.x * 64, by = blockIdx.y * 64;
    int tx = threadIdx.x & 63, ty = threadIdx.x >> 6;
    for (int i = ty; i < 64; i += 4)
        tile[i][tx] = in[(size_t)(by + i) * cols + bx + tx];
    __syncthreads();
    for (int i = ty; i < 64; i += 4)
        out[(size_t)(bx + i) * rows + by + tx] = f2bf(tile[tx][i]);
}

// ---------------------------------------------------------------------------
// GEMM1 fused with pixel-unshuffle (split-K=2):
//   P[z][8192][768] = unshuffle(x) @ WqkvT^T
// A-fragments (8 consecutive token-channels) are 8 contiguous f32 in x:
//   addr = ((b*64+c0)*256 + yy*8 + r1)*256 + xx*8
// so A is reg-staged (dwordx4 x2 -> v_cvt_pk_bf16_f32 -> ds_write_b128) into
// the same LDS layout the m97 structure expects. B keeps global_load_lds.
// XCD-chunked swizzle: 8 tm-panels per XCD, (tn, z) innermost, so the 12
// blocks sharing one A-panel are co-resident on one XCD's L2.
// grid = 768x1x1, block 256.
// ---------------------------------------------------------------------------
__global__ __launch_bounds__(256) void k_gemm_qkv(const float* __restrict__ x,
                                                  const u16* __restrict__ Bt,
                                                  float* __restrict__ P) {
    const int K = 4096;
    __shared__ u16 As[128 * 64];
    __shared__ u16 Bs[128 * 64];
    const int tid = threadIdx.x;
    const int wave = tid >> 6, lane = tid & 63;
    const int quad = lane >> 4, l15 = lane & 15;
    const int wm = wave >> 1, wn = wave & 1;

    // XCD-chunked bijective swizzle (768 % 8 == 0): xcd gets rem in
    // [xcd*96, xcd*96+96) -> tmi in [xcd*8, xcd*8+8).
    int lin = blockIdx.x;
    int rem = (lin & 7) * 96 + (lin >> 3);
    int tn6 = rem % 6;
    int rq  = rem / 6;          // 0..127
    int z   = rq & 1;
    int tmi = rq >> 1;          // 0..63
    const int tm = tmi * 128, tn = tn6 * 128;

    // Per-thread A source pointers into x; advance by one c0 (65536 f32)
    // per K-step of 64.
    const float* aptr[4];
#pragma unroll
    for (int t = 0; t < 4; ++t) {
        int cidx = wave * 256 + t * 64 + lane;   // 0..1023
        int row = cidx >> 3, kc = cidx & 7;
        int m = tm + row;
        int b = m >> 10, n = m & 1023, yy = n >> 5, xx = n & 31;
        aptr[t] = x + (size_t)b * 4194304 + (size_t)z * 2097152
                    + (yy * 8 + kc) * 256 + xx * 8;
    }

    f32x4 acc[4][4] = {};

    for (int k0 = z * 2048; k0 < (z + 1) * 2048; k0 += 64) {
        // Issue A loads (global, no LDS hazard) before the barrier so they
        // overlap the previous iteration's MFMA tail.
        float4 va[4][2];
#pragma unroll
        for (int t = 0; t < 4; ++t) {
            const float4* sp = (const float4*)aptr[t];
            va[t][0] = sp[0];
            va[t][1] = sp[1];
            aptr[t] += 65536;
        }
        __syncthreads();
        // B tile: async global->LDS, width 16
#pragma unroll
        for (int t = 0; t < 4; ++t) {
            int c = wave * 256 + t * 64 + lane;
            int row = c >> 3, kc = c & 7;
            gl_lds16(Bt + (size_t)(tn + row) * K + k0 + kc * 8,
                     Bs + (wave * 256 + t * 64) * 8);
        }
        // A tile: convert 8 f32 -> 8 bf16 per (t), one ds_write_b128 each
#pragma unroll
        for (int t = 0; t < 4; ++t) {
            int cidx = wave * 256 + t * 64 + lane;
            uint4 pk;
            pk.x = cvt_pk_bf16(va[t][0].x, va[t][0].y);
            pk.y = cvt_pk_bf16(va[t][0].z, va[t][0].w);
            pk.z = cvt_pk_bf16(va[t][1].x, va[t][1].y);
            pk.w = cvt_pk_bf16(va[t][1].z, va[t][1].w);
            *(uint4*)(As + cidx * 8) = pk;
        }
        __syncthreads();
        for (int kk = 0; kk < 64; kk += 32) {
            s16x8 af[4], bf[4];
            for (int i = 0; i < 4; ++i)
                af[i] = *(const s16x8*)(As + (wm * 64 + i * 16 + l15) * 64 + kk + quad * 8);
            for (int j = 0; j < 4; ++j)
                bf[j] = *(const s16x8*)(Bs + (wn * 64 + j * 16 + l15) * 64 + kk + quad * 8);
            for (int i = 0; i < 4; ++i)
                for (int j = 0; j < 4; ++j)
                    acc[i][j] = __builtin_amdgcn_mfma_f32_16x16x32_bf16(af[i], bf[j], acc[i][j], 0, 0, 0);
        }
    }

    float* Pz = P + (size_t)z * 8192 * 768;
    for (int i = 0; i < 4; ++i) {
        int mb = tm + wm * 64 + i * 16 + quad * 4;
        for (int j = 0; j < 4; ++j) {
            int col = tn + wn * 64 + j * 16 + l15;
            for (int r = 0; r < 4; ++r)
                Pz[(size_t)(mb + r) * 768 + col] = acc[i][j][r];
        }
    }
}

// ---------------------------------------------------------------------------
// Split-K reduce + scatter. Q,K -> [bh][n][d]; V -> TRANSPOSED Vt[bh][d][n]
// (64x65-padded LDS tile transpose; both global sides coalesced).
// grid (12, 128), block 256.
// ---------------------------------------------------------------------------
__global__ __launch_bounds__(256) void k_qkv_reduce(const float* __restrict__ P,
                                                    u16* __restrict__ Qo,
                                                    u16* __restrict__ Ko,
                                                    u16* __restrict__ Vt) {
    __shared__ u16 tile[64][65];
    const int tid = threadIdx.x;
    const int ct = blockIdx.x, mt = blockIdx.y;
    const int c_l = tid & 63;
    const int col = ct * 64 + c_l;
    const int mbase = mt * 64;
    const float* P1 = P + (size_t)8192 * 768;

    if (ct < 8) {                       // Q (ct<4) / K (ct>=4), direct store
        int which = col >> 8;
        int h = (col >> 6) & 3, d = col & 63;
        u16* dst = (which == 0) ? Qo : Ko;
        for (int k = 0; k < 16; ++k) {
            int m = mbase + (tid >> 6) + k * 4;
            float v = P[(size_t)m * 768 + col] + P1[(size_t)m * 768 + col];
            int b = m >> 10, n = m & 1023;
            dst[((size_t)((b * 4 + h) * 1024 + n)) * 64 + d] = f2bf(v);
        }
    } else {                            // V: transpose to Vt[bh][d][n]
        int h = ct - 8;
        int b = mbase >> 10;
        int nbase = mbase & 1023;
        for (int k = 0; k < 16; ++k) {
            int ml = (tid >> 6) + k * 4;
            int m = mbase + ml;
            float v = P[(size_t)m * 768 + col] + P1[(size_t)m * 768 + col];
            tile[ml][c_l] = f2bf(v);
        }
        __syncthreads();
        for (int k = 0; k < 16; ++k) {
            int d = (tid >> 6) + k * 4;
            Vt[((size_t)((b * 4 + h) * 64 + d)) * 1024 + nbase + c_l] = tile[c_l][d];
        }
    }
}

// ---------------------------------------------------------------------------
// Flash attention. K tile: flat 8KB contiguous -> global_load_lds width16.
// V pre-transposed in global (Vt[bh][d][n]) -> vector load + ds_write_b128
// into padded Vts[64][68]. grid (16, 32), block 256.
// ---------------------------------------------------------------------------
__global__ __launch_bounds__(256) void k_attn(const u16* __restrict__ Qb,
                                              const u16* __restrict__ Kb,
                                              const u16* __restrict__ Vt,
                                              u16* __restrict__ aout) {
    const int bh = blockIdx.y;
    const int q0 = blockIdx.x * 64;
    const int tid = threadIdx.x;
    const int wave = tid >> 6, lane = tid & 63;
    const int quad = lane >> 4, l15 = lane & 15;
    const size_t base = (size_t)bh * 1024 * 64;
    const float scale = 0.125f;

    __shared__ u16 Ks[64 * 64];
    __shared__ u16 Vts[64 * 68];     // [d][kv], pad 68
    __shared__ u16 Ps[4][16 * 64];   // per-wave P scratch

    s16x8 aq0, aq1;
    {
        const u16* qp = Qb + base + (size_t)(q0 + wave * 16 + l15) * 64 + quad * 8;
        aq0 = *(const s16x8*)(qp);
        aq1 = *(const s16x8*)(qp + 32);
    }

    float m_i[4], l_i[4];
    f32x4 o[4] = {};
    for (int r = 0; r < 4; ++r) { m_i[r] = -1e30f; l_i[r] = 0.f; }

    const int vrow = tid >> 2, vpart = tid & 3;

    for (int t = 0; t < 16; ++t) {
        __syncthreads();
        // K tile: 4096 contiguous u16 -> LDS, async 16B per lane
        for (int e = 0; e < 2; ++e) {
            int s = e * 256 + tid;
            gl_lds16(Kb + base + (size_t)t * 4096 + s * 8, Ks + s * 8);
        }
        // V tile from Vt: row vrow, 16 u16 per thread, ds_write_b128 x2
        {
            const u16* src = Vt + base + (size_t)vrow * 1024 + t * 64 + vpart * 16;
            s16x8 a = *(const s16x8*)(src);
            s16x8 b2 = *(const s16x8*)(src + 8);
            *(s16x8*)(Vts + vrow * 68 + vpart * 16) = a;
            *(s16x8*)(Vts + vrow * 68 + vpart * 16 + 8) = b2;
        }
        __syncthreads();

        // S = Q K^T (wave: 16 q-rows x 64 kv-cols)
        f32x4 s4[4];
        for (int j = 0; j < 4; ++j) {
            const u16* kr = Ks + (j * 16 + l15) * 64 + quad * 8;
            s16x8 b0 = *(const s16x8*)(kr);
            s16x8 b1 = *(const s16x8*)(kr + 32);
            f32x4 c = {};
            c = __builtin_amdgcn_mfma_f32_16x16x32_bf16(aq0, b0, c, 0, 0, 0);
            c = __builtin_amdgcn_mfma_f32_16x16x32_bf16(aq1, b1, c, 0, 0, 0);
            s4[j] = c;
        }

        // online softmax; lane's rows are quad*4 + r
        for (int r = 0; r < 4; ++r) {
            float sv0 = s4[0][r] * scale, sv1 = s4[1][r] * scale;
            float sv2 = s4[2][r] * scale, sv3 = s4[3][r] * scale;
            float mt = fmaxf(fmaxf(sv0, sv1), fmaxf(sv2, sv3));
            for (int off = 1; off < 16; off <<= 1)
                mt = fmaxf(mt, __shfl_xor(mt, off, 64));
            float mn = fmaxf(m_i[r], mt);
            float alpha = __expf(m_i[r] - mn);
            m_i[r] = mn;
            float p0 = __expf(sv0 - mn), p1 = __expf(sv1 - mn);
            float p2 = __expf(sv2 - mn), p3 = __expf(sv3 - mn);
            u16* pw = Ps[wave] + (quad * 4 + r) * 64 + l15;
            pw[0]  = f2bf(p0);
            pw[16] = f2bf(p1);
            pw[32] = f2bf(p2);
            pw[48] = f2bf(p3);
            float rs = p0 + p1 + p2 + p3;
            for (int off = 1; off < 16; off <<= 1)
                rs += __shfl_xor(rs, off, 64);
            l_i[r] = l_i[r] * alpha + rs;
            for (int dt = 0; dt < 4; ++dt) o[dt][r] *= alpha;
        }

        // O += P @ V
        for (int kk = 0; kk < 64; kk += 32) {
            s16x8 pf = *(const s16x8*)(Ps[wave] + l15 * 64 + kk + quad * 8);
            for (int dt = 0; dt < 4; ++dt) {
                const u16* vr = Vts + (dt * 16 + l15) * 68 + kk + quad * 8;
                s16x4 v0 = *(const s16x4*)(vr);
                s16x4 v1 = *(const s16x4*)(vr + 4);
                s16x8 vf;
                vf[0] = v0[0]; vf[1] = v0[1]; vf[2] = v0[2]; vf[3] = v0[3];
                vf[4] = v1[0]; vf[5] = v1[1]; vf[6] = v1[2]; vf[7] = v1[3];
                o[dt] = __builtin_amdgcn_mfma_f32_16x16x32_bf16(pf, vf, o[dt], 0, 0, 0);
            }
        }
    }

    int b = bh >> 2, h = bh & 3;
    float rl[4];
    for (int r = 0; r < 4; ++r) rl[r] = 1.0f / l_i[r];
    for (int dt = 0; dt < 4; ++dt)
        for (int r = 0; r < 4; ++r) {
            int qrow = q0 + wave * 16 + quad * 4 + r;
            aout[((size_t)(b) * 1024 + qrow) * 256 + h * 64 + dt * 16 + l15] =
                f2bf(o[dt][r] * rl[r]);
        }
}

// ---------------------------------------------------------------------------
// GEMM2: y[8192][4096] = aout[8192][256] @ W_outT^T + bias, fused shuffle.
// ---------------------------------------------------------------------------
__global__ __launch_bounds__(256) void k_gemm_out(const u16* __restrict__ A,
                                                  const u16* __restrict__ Bt,
                                                  const float* __restrict__ bias,
                                                  float* __restrict__ out) {
    const int K = 256;
    __shared__ u16 As[128 * 64];
    __shared__ u16 Bs[128 * 64];
    const int tid = threadIdx.x;
    const int wave = tid >> 6, lane = tid & 63;
    const int quad = lane >> 4, l15 = lane & 15;
    const int wm = wave >> 1, wn = wave & 1;
    const int tm = blockIdx.y * 128, tn = blockIdx.x * 128;

    f32x4 acc[4][4] = {};

    for (int k0 = 0; k0 < K; k0 += 64) {
        __syncthreads();
        for (int t = 0; t < 4; ++t) {
            int c = wave * 256 + t * 64 + lane;
            int row = c >> 3, kc = c & 7;
            gl_lds16(A + (size_t)(tm + row) * K + k0 + kc * 8,
                     As + (wave * 256 + t * 64) * 8);
        }
        for (int t = 0; t < 4; ++t) {
            int c = wave * 256 + t * 64 + lane;
            int row = c >> 3, kc = c & 7;
            gl_lds16(Bt + (size_t)(tn + row) * K + k0 + kc * 8,
                     Bs + (wave * 256 + t * 64) * 8);
        }
        __syncthreads();
        for (int kk = 0; kk < 64; kk += 32) {
            s16x8 af[4], bf[4];
            for (int i = 0; i < 4; ++i)
                af[i] = *(const s16x8*)(As + (wm * 64 + i * 16 + l15) * 64 + kk + quad * 8);
            for (int j = 0; j < 4; ++j)
                bf[j] = *(const s16x8*)(Bs + (wn * 64 + j * 16 + l15) * 64 + kk + quad * 8);
            for (int i = 0; i < 4; ++i)
                for (int j = 0; j < 4; ++j)
                    acc[i][j] = __builtin_amdgcn_mfma_f32_16x16x32_bf16(af[i], bf[j], acc[i][j], 0, 0, 0);
        }
    }

    for (int i = 0; i < 4; ++i) {
        int mb = tm + wm * 64 + i * 16 + quad * 4;
        for (int j = 0; j < 4; ++j) {
            int col = tn + wn * 64 + j * 16 + l15;
            float bb = bias[col];
            int c0 = col >> 6, r1 = (col >> 3) & 7, r2 = col & 7;
            for (int r = 0; r < 4; ++r) {
                int m = mb + r;
                int b = m >> 10, n = m & 1023, yy = n >> 5, xx = n & 31;
                size_t oidx = ((size_t)((b * 64 + c0) * 256 + yy * 8 + r1)) * 256 + xx * 8 + r2;
                out[oidx] = acc[i][j][r] + bb;
            }
        }
    }
}

// ---------------------------------------------------------------------------
extern "C" void kernel_launch(void* const* d_in, const int* in_sizes, int n_in,
                              void* d_out, int out_size, void* d_ws, size_t ws_size,
                              hipStream_t stream) {
    (void)in_sizes; (void)n_in; (void)out_size; (void)ws_size;
    const float* x    = (const float*)d_in[0];
    const float* Wqkv = (const float*)d_in[1];   // [4096][768]
    const float* Wout = (const float*)d_in[2];   // [256][4096]
    const float* bout = (const float*)d_in[3];   // [4096]
    float* out = (float*)d_out;

    u16* ws     = (u16*)d_ws;
    u16* wqkvT  = ws;                        // 768*4096
    u16* woutT  = wqkvT + 3145728;           // 4096*256
    u16* Qb     = woutT + 1048576;           // 32*1024*64
    u16* Kb     = Qb + 2097152;
    u16* Vtb    = Kb + 2097152;              // V transposed [bh][d][n]
    u16* aoutb  = Vtb + 2097152;             // 8192*256
    float* Pp   = (float*)(aoutb + 2097152); // 2*8192*768 f32

    k_transpose<<<dim3(12, 64), 256, 0, stream>>>(Wqkv, wqkvT, 4096, 768);
    k_transpose<<<dim3(64, 4), 256, 0, stream>>>(Wout, woutT, 256, 4096);
    k_gemm_qkv<<<dim3(768, 1, 1), 256, 0, stream>>>(x, wqkvT, Pp);
    k_qkv_reduce<<<dim3(12, 128), 256, 0, stream>>>(Pp, Qb, Kb, Vtb);
    k_attn<<<dim3(16, 32), 256, 0, stream>>>(Qb, Kb, Vtb, aoutb);
    k_gemm_out<<<dim3(32, 64), 256, 0, stream>>>(aoutb, woutT, bout, out);
}

// Round 2
// 413.013 us; speedup vs baseline: 1.1500x; 1.1500x over previous
//
#include <hip/hip_runtime.h>

typedef unsigned short u16;
typedef __attribute__((ext_vector_type(8))) short s16x8;
typedef __attribute__((ext_vector_type(4))) short s16x4;
typedef __attribute__((ext_vector_type(4))) float f32x4;

__device__ __forceinline__ u16 f2bf(float f) {
    unsigned int u;
    __builtin_memcpy(&u, &f, 4);
    unsigned int r = u + 0x7FFFu + ((u >> 16) & 1u);   // RNE
    return (u16)(r >> 16);
}

// packed f32 pair -> bf16 pair (RNE), lo = cvt(a), hi = cvt(b)
__device__ __forceinline__ unsigned int cvt_pk_bf16(float a, float b) {
    unsigned int r;
    asm("v_cvt_pk_bf16_f32 %0, %1, %2" : "=v"(r) : "v"(a), "v"(b));
    return r;
}

__device__ __forceinline__ void gl_lds16(const u16* g, u16* l) {
    __builtin_amdgcn_global_load_lds(
        (const __attribute__((address_space(1))) unsigned int*)g,
        (__attribute__((address_space(3))) unsigned int*)l,
        16, 0, 0);
}

// ---------------------------------------------------------------------------
// Transpose f32 -> bf16: out[c][r] = bf16(in[r][c]). grid = (cols/64, rows/64)
// ---------------------------------------------------------------------------
__global__ __launch_bounds__(256) void k_transpose(const float* __restrict__ in,
                                                   u16* __restrict__ out,
                                                   int rows, int cols) {
    __shared__ float tile[64][65];
    int bx = blockIdx.x * 64, by = blockIdx.y * 64;
    int tx = threadIdx.x & 63, ty = threadIdx.x >> 6;
    for (int i = ty; i < 64; i += 4)
        tile[i][tx] = in[(size_t)(by + i) * cols + bx + tx];
    __syncthreads();
    for (int i = ty; i < 64; i += 4)
        out[(size_t)(bx + i) * rows + by + tx] = f2bf(tile[tx][i]);
}

// ---------------------------------------------------------------------------
// GEMM1 fused with pixel-unshuffle (split-K=2):
//   P[z][8192][768] = unshuffle(x) @ WqkvT^T
// Fixed staging (round-1 post-mortem): per K-step the A-source is ONE
// CONTIGUOUS 32KB block of x -> thread tid reads tt*2048 + tid*8 f32
// (coalesced 2KB/wave), prefetched ONE ITERATION AHEAD (issued after
// barrier2 so latency hides under the MFMA phase), converted with
// v_cvt_pk_bf16_f32 and stored via ds_write_b128 into an XOR-SWIZZLED
// As (byte ^= (row&7)<<4, same involution on read) -> bank-conflict-free
// both sides. B keeps global_load_lds into linear Bs.
// grid = 768x1x1, block 256.
// ---------------------------------------------------------------------------
__global__ __launch_bounds__(256) void k_gemm_qkv(const float* __restrict__ x,
                                                  const u16* __restrict__ Bt,
                                                  float* __restrict__ P) {
    const int K = 4096;
    __shared__ u16 As[128 * 64];   // XOR-swizzled
    __shared__ u16 Bs[128 * 64];   // linear
    const int tid = threadIdx.x;
    const int wave = tid >> 6, lane = tid & 63;
    const int quad = lane >> 4, l15 = lane & 15;
    const int wm = wave >> 1, wn = wave & 1;

    // XCD-chunked bijective swizzle (768 % 8 == 0)
    int lin = blockIdx.x;
    int rem = (lin & 7) * 96 + (lin >> 3);
    int tn6 = rem % 6;
    int rq  = rem / 6;          // 0..127
    int z   = rq & 1;
    int tmi = rq >> 1;          // 0..63
    const int tm = tmi * 128, tn = tn6 * 128;

    // ---- A-staging geometry ----
    // tile rows tm..tm+127 = batch b, yy in [yy0, yy0+4), all xx.
    // Per K-step (one c0) the source is contiguous:
    //   x + (b*64 + c0)*65536 + yy0*2048, 8192 f32.
    // Thread reads 4 chunks of 8 f32 at  tt*2048 + tid*8:
    //   row-in-tile = tt*32 + (tid&31),  channel group r1 = (tid>>5)&7.
    const int b   = tm >> 10;
    const int yy0 = (tm & 1023) >> 5;
    const float* asrc = x + ((size_t)(b * 64 + z * 32)) * 65536 + yy0 * 2048 + tid * 8;

    u16* dstA[4];
#pragma unroll
    for (int t = 0; t < 4; ++t) {
        int row = t * 32 + (tid & 31);
        int r1  = (tid >> 5) & 7;
        int byteoff = (row * 128 + r1 * 16) ^ ((tid & 7) << 4);
        dstA[t] = (u16*)((char*)As + byteoff);
    }

    // prologue: prefetch iter 0
    float4 va[4][2];
#pragma unroll
    for (int t = 0; t < 4; ++t) {
        const float4* sp = (const float4*)(asrc + t * 2048);
        va[t][0] = sp[0];
        va[t][1] = sp[1];
    }

    f32x4 acc[4][4] = {};

    for (int it = 0; it < 32; ++it) {
        int k0 = z * 2048 + it * 64;
        __syncthreads();
        // B tile: async global->LDS, width 16
#pragma unroll
        for (int t = 0; t < 4; ++t) {
            int c = wave * 256 + t * 64 + lane;
            int row = c >> 3, kc = c & 7;
            gl_lds16(Bt + (size_t)(tn + row) * K + k0 + kc * 8,
                     Bs + (wave * 256 + t * 64) * 8);
        }
        // A tile: cvt 8 f32 -> 8 bf16, one swizzled ds_write_b128 per t
#pragma unroll
        for (int t = 0; t < 4; ++t) {
            uint4 pk;
            pk.x = cvt_pk_bf16(va[t][0].x, va[t][0].y);
            pk.y = cvt_pk_bf16(va[t][0].z, va[t][0].w);
            pk.z = cvt_pk_bf16(va[t][1].x, va[t][1].y);
            pk.w = cvt_pk_bf16(va[t][1].z, va[t][1].w);
            *(uint4*)dstA[t] = pk;
        }
        __syncthreads();
        // prefetch next iter's A during the MFMA phase
        if (it < 31) {
            asrc += 65536;
#pragma unroll
            for (int t = 0; t < 4; ++t) {
                const float4* sp = (const float4*)(asrc + t * 2048);
                va[t][0] = sp[0];
                va[t][1] = sp[1];
            }
        }
        // MFMA (A reads apply the same XOR involution)
        for (int kk = 0; kk < 64; kk += 32) {
            s16x8 af[4], bf[4];
            for (int i = 0; i < 4; ++i) {
                int row = wm * 64 + i * 16 + l15;
                int byteoff = (row * 128 + kk * 2 + quad * 16) ^ ((l15 & 7) << 4);
                af[i] = *(const s16x8*)((const char*)As + byteoff);
            }
            for (int j = 0; j < 4; ++j)
                bf[j] = *(const s16x8*)(Bs + (wn * 64 + j * 16 + l15) * 64 + kk + quad * 8);
            for (int i = 0; i < 4; ++i)
                for (int j = 0; j < 4; ++j)
                    acc[i][j] = __builtin_amdgcn_mfma_f32_16x16x32_bf16(af[i], bf[j], acc[i][j], 0, 0, 0);
        }
    }

    float* Pz = P + (size_t)z * 8192 * 768;
    for (int i = 0; i < 4; ++i) {
        int mb = tm + wm * 64 + i * 16 + quad * 4;
        for (int j = 0; j < 4; ++j) {
            int col = tn + wn * 64 + j * 16 + l15;
            for (int r = 0; r < 4; ++r)
                Pz[(size_t)(mb + r) * 768 + col] = acc[i][j][r];
        }
    }
}

// ---------------------------------------------------------------------------
// Split-K reduce + scatter. Q,K -> [bh][n][d]; V -> TRANSPOSED Vt[bh][d][n]
// (64x65-padded LDS tile transpose; both global sides coalesced).
// grid (12, 128), block 256.
// ---------------------------------------------------------------------------
__global__ __launch_bounds__(256) void k_qkv_reduce(const float* __restrict__ P,
                                                    u16* __restrict__ Qo,
                                                    u16* __restrict__ Ko,
                                                    u16* __restrict__ Vt) {
    __shared__ u16 tile[64][65];
    const int tid = threadIdx.x;
    const int ct = blockIdx.x, mt = blockIdx.y;
    const int c_l = tid & 63;
    const int col = ct * 64 + c_l;
    const int mbase = mt * 64;
    const float* P1 = P + (size_t)8192 * 768;

    if (ct < 8) {                       // Q (ct<4) / K (ct>=4), direct store
        int which = col >> 8;
        int h = (col >> 6) & 3, d = col & 63;
        u16* dst = (which == 0) ? Qo : Ko;
        for (int k = 0; k < 16; ++k) {
            int m = mbase + (tid >> 6) + k * 4;
            float v = P[(size_t)m * 768 + col] + P1[(size_t)m * 768 + col];
            int b = m >> 10, n = m & 1023;
            dst[((size_t)((b * 4 + h) * 1024 + n)) * 64 + d] = f2bf(v);
        }
    } else {                            // V: transpose to Vt[bh][d][n]
        int h = ct - 8;
        int b = mbase >> 10;
        int nbase = mbase & 1023;
        for (int k = 0; k < 16; ++k) {
            int ml = (tid >> 6) + k * 4;
            int m = mbase + ml;
            float v = P[(size_t)m * 768 + col] + P1[(size_t)m * 768 + col];
            tile[ml][c_l] = f2bf(v);
        }
        __syncthreads();
        for (int k = 0; k < 16; ++k) {
            int d = (tid >> 6) + k * 4;
            Vt[((size_t)((b * 4 + h) * 64 + d)) * 1024 + nbase + c_l] = tile[c_l][d];
        }
    }
}

// ---------------------------------------------------------------------------
// Flash attention. K tile: flat 8KB contiguous -> global_load_lds width16.
// V pre-transposed in global (Vt[bh][d][n]) -> vector load + ds_write_b128
// into padded Vts[64][68]. grid (16, 32), block 256.
// ---------------------------------------------------------------------------
__global__ __launch_bounds__(256) void k_attn(const u16* __restrict__ Qb,
                                              const u16* __restrict__ Kb,
                                              const u16* __restrict__ Vt,
                                              u16* __restrict__ aout) {
    const int bh = blockIdx.y;
    const int q0 = blockIdx.x * 64;
    const int tid = threadIdx.x;
    const int wave = tid >> 6, lane = tid & 63;
    const int quad = lane >> 4, l15 = lane & 15;
    const size_t base = (size_t)bh * 1024 * 64;
    const float scale = 0.125f;

    __shared__ u16 Ks[64 * 64];
    __shared__ u16 Vts[64 * 68];     // [d][kv], pad 68
    __shared__ u16 Ps[4][16 * 64];   // per-wave P scratch

    s16x8 aq0, aq1;
    {
        const u16* qp = Qb + base + (size_t)(q0 + wave * 16 + l15) * 64 + quad * 8;
        aq0 = *(const s16x8*)(qp);
        aq1 = *(const s16x8*)(qp + 32);
    }

    float m_i[4], l_i[4];
    f32x4 o[4] = {};
    for (int r = 0; r < 4; ++r) { m_i[r] = -1e30f; l_i[r] = 0.f; }

    const int vrow = tid >> 2, vpart = tid & 3;

    for (int t = 0; t < 16; ++t) {
        __syncthreads();
        // K tile: 4096 contiguous u16 -> LDS, async 16B per lane
        for (int e = 0; e < 2; ++e) {
            int s = e * 256 + tid;
            gl_lds16(Kb + base + (size_t)t * 4096 + s * 8, Ks + s * 8);
        }
        // V tile from Vt: row vrow, 16 u16 per thread, ds_write_b128 x2
        {
            const u16* src = Vt + base + (size_t)vrow * 1024 + t * 64 + vpart * 16;
            s16x8 a = *(const s16x8*)(src);
            s16x8 b2 = *(const s16x8*)(src + 8);
            *(s16x8*)(Vts + vrow * 68 + vpart * 16) = a;
            *(s16x8*)(Vts + vrow * 68 + vpart * 16 + 8) = b2;
        }
        __syncthreads();

        // S = Q K^T (wave: 16 q-rows x 64 kv-cols)
        f32x4 s4[4];
        for (int j = 0; j < 4; ++j) {
            const u16* kr = Ks + (j * 16 + l15) * 64 + quad * 8;
            s16x8 b0 = *(const s16x8*)(kr);
            s16x8 b1 = *(const s16x8*)(kr + 32);
            f32x4 c = {};
            c = __builtin_amdgcn_mfma_f32_16x16x32_bf16(aq0, b0, c, 0, 0, 0);
            c = __builtin_amdgcn_mfma_f32_16x16x32_bf16(aq1, b1, c, 0, 0, 0);
            s4[j] = c;
        }

        // online softmax; lane's rows are quad*4 + r
        for (int r = 0; r < 4; ++r) {
            float sv0 = s4[0][r] * scale, sv1 = s4[1][r] * scale;
            float sv2 = s4[2][r] * scale, sv3 = s4[3][r] * scale;
            float mt = fmaxf(fmaxf(sv0, sv1), fmaxf(sv2, sv3));
            for (int off = 1; off < 16; off <<= 1)
                mt = fmaxf(mt, __shfl_xor(mt, off, 64));
            float mn = fmaxf(m_i[r], mt);
            float alpha = __expf(m_i[r] - mn);
            m_i[r] = mn;
            float p0 = __expf(sv0 - mn), p1 = __expf(sv1 - mn);
            float p2 = __expf(sv2 - mn), p3 = __expf(sv3 - mn);
            u16* pw = Ps[wave] + (quad * 4 + r) * 64 + l15;
            pw[0]  = f2bf(p0);
            pw[16] = f2bf(p1);
            pw[32] = f2bf(p2);
            pw[48] = f2bf(p3);
            float rs = p0 + p1 + p2 + p3;
            for (int off = 1; off < 16; off <<= 1)
                rs += __shfl_xor(rs, off, 64);
            l_i[r] = l_i[r] * alpha + rs;
            for (int dt = 0; dt < 4; ++dt) o[dt][r] *= alpha;
        }

        // O += P @ V
        for (int kk = 0; kk < 64; kk += 32) {
            s16x8 pf = *(const s16x8*)(Ps[wave] + l15 * 64 + kk + quad * 8);
            for (int dt = 0; dt < 4; ++dt) {
                const u16* vr = Vts + (dt * 16 + l15) * 68 + kk + quad * 8;
                s16x4 v0 = *(const s16x4*)(vr);
                s16x4 v1 = *(const s16x4*)(vr + 4);
                s16x8 vf;
                vf[0] = v0[0]; vf[1] = v0[1]; vf[2] = v0[2]; vf[3] = v0[3];
                vf[4] = v1[0]; vf[5] = v1[1]; vf[6] = v1[2]; vf[7] = v1[3];
                o[dt] = __builtin_amdgcn_mfma_f32_16x16x32_bf16(pf, vf, o[dt], 0, 0, 0);
            }
        }
    }

    int b = bh >> 2, h = bh & 3;
    float rl[4];
    for (int r = 0; r < 4; ++r) rl[r] = 1.0f / l_i[r];
    for (int dt = 0; dt < 4; ++dt)
        for (int r = 0; r < 4; ++r) {
            int qrow = q0 + wave * 16 + quad * 4 + r;
            aout[((size_t)(b) * 1024 + qrow) * 256 + h * 64 + dt * 16 + l15] =
                f2bf(o[dt][r] * rl[r]);
        }
}

// ---------------------------------------------------------------------------
// GEMM2: y[8192][4096] = aout[8192][256] @ W_outT^T + bias, fused shuffle.
// ---------------------------------------------------------------------------
__global__ __launch_bounds__(256) void k_gemm_out(const u16* __restrict__ A,
                                                  const u16* __restrict__ Bt,
                                                  const float* __restrict__ bias,
                                                  float* __restrict__ out) {
    const int K = 256;
    __shared__ u16 As[128 * 64];
    __shared__ u16 Bs[128 * 64];
    const int tid = threadIdx.x;
    const int wave = tid >> 6, lane = tid & 63;
    const int quad = lane >> 4, l15 = lane & 15;
    const int wm = wave >> 1, wn = wave & 1;
    const int tm = blockIdx.y * 128, tn = blockIdx.x * 128;

    f32x4 acc[4][4] = {};

    for (int k0 = 0; k0 < K; k0 += 64) {
        __syncthreads();
        for (int t = 0; t < 4; ++t) {
            int c = wave * 256 + t * 64 + lane;
            int row = c >> 3, kc = c & 7;
            gl_lds16(A + (size_t)(tm + row) * K + k0 + kc * 8,
                     As + (wave * 256 + t * 64) * 8);
        }
        for (int t = 0; t < 4; ++t) {
            int c = wave * 256 + t * 64 + lane;
            int row = c >> 3, kc = c & 7;
            gl_lds16(Bt + (size_t)(tn + row) * K + k0 + kc * 8,
                     Bs + (wave * 256 + t * 64) * 8);
        }
        __syncthreads();
        for (int kk = 0; kk < 64; kk += 32) {
            s16x8 af[4], bf[4];
            for (int i = 0; i < 4; ++i)
                af[i] = *(const s16x8*)(As + (wm * 64 + i * 16 + l15) * 64 + kk + quad * 8);
            for (int j = 0; j < 4; ++j)
                bf[j] = *(const s16x8*)(Bs + (wn * 64 + j * 16 + l15) * 64 + kk + quad * 8);
            for (int i = 0; i < 4; ++i)
                for (int j = 0; j < 4; ++j)
                    acc[i][j] = __builtin_amdgcn_mfma_f32_16x16x32_bf16(af[i], bf[j], acc[i][j], 0, 0, 0);
        }
    }

    for (int i = 0; i < 4; ++i) {
        int mb = tm + wm * 64 + i * 16 + quad * 4;
        for (int j = 0; j < 4; ++j) {
            int col = tn + wn * 64 + j * 16 + l15;
            float bb = bias[col];
            int c0 = col >> 6, r1 = (col >> 3) & 7, r2 = col & 7;
            for (int r = 0; r < 4; ++r) {
                int m = mb + r;
                int b = m >> 10, n = m & 1023, yy = n >> 5, xx = n & 31;
                size_t oidx = ((size_t)((b * 64 + c0) * 256 + yy * 8 + r1)) * 256 + xx * 8 + r2;
                out[oidx] = acc[i][j][r] + bb;
            }
        }
    }
}

// ---------------------------------------------------------------------------
extern "C" void kernel_launch(void* const* d_in, const int* in_sizes, int n_in,
                              void* d_out, int out_size, void* d_ws, size_t ws_size,
                              hipStream_t stream) {
    (void)in_sizes; (void)n_in; (void)out_size; (void)ws_size;
    const float* x    = (const float*)d_in[0];
    const float* Wqkv = (const float*)d_in[1];   // [4096][768]
    const float* Wout = (const float*)d_in[2];   // [256][4096]
    const float* bout = (const float*)d_in[3];   // [4096]
    float* out = (float*)d_out;

    u16* ws     = (u16*)d_ws;
    u16* wqkvT  = ws;                        // 768*4096
    u16* woutT  = wqkvT + 3145728;           // 4096*256
    u16* Qb     = woutT + 1048576;           // 32*1024*64
    u16* Kb     = Qb + 2097152;
    u16* Vtb    = Kb + 2097152;              // V transposed [bh][d][n]
    u16* aoutb  = Vtb + 2097152;             // 8192*256
    float* Pp   = (float*)(aoutb + 2097152); // 2*8192*768 f32

    k_transpose<<<dim3(12, 64), 256, 0, stream>>>(Wqkv, wqkvT, 4096, 768);
    k_transpose<<<dim3(64, 4), 256, 0, stream>>>(Wout, woutT, 256, 4096);
    k_gemm_qkv<<<dim3(768, 1, 1), 256, 0, stream>>>(x, wqkvT, Pp);
    k_qkv_reduce<<<dim3(12, 128), 256, 0, stream>>>(Pp, Qb, Kb, Vtb);
    k_attn<<<dim3(16, 32), 256, 0, stream>>>(Qb, Kb, Vtb, aoutb);
    k_gemm_out<<<dim3(32, 64), 256, 0, stream>>>(aoutb, woutT, bout, out);
}